// Round 19
// baseline (81.486 us; speedup 1.0000x reference)
//
#include <hip/hip_runtime.h>
#include <hip/hip_bf16.h>

#define Bc 2
#define Hc 16
#define Sc 2048
#define Dc 1024

typedef __attribute__((ext_vector_type(8))) short s16x8;
typedef __attribute__((ext_vector_type(4))) float f32x4;
typedef __attribute__((ext_vector_type(16))) float f32x16;

#define AS1 __attribute__((address_space(1)))
#define AS3 __attribute__((address_space(3)))

// LDS chunk swizzle (involution): distinct across rows differing by 8/16/24
// (the ds_read alias groups) -> bank-conflict-free (verified r16: 4.2M -> 0).
static __device__ __forceinline__ int swz(int row) {
    return (row & 7) ^ ((row >> 3) & 3);
}

static __device__ __forceinline__ float fexp2(float x) {
#if __has_builtin(__builtin_amdgcn_exp2f)
    return __builtin_amdgcn_exp2f(x);
#else
    float r; asm("v_exp_f32 %0, %1" : "=v"(r) : "v"(x)); return r;
#endif
}

// pack two f32 -> one u32 of 2 bf16 (RTNE), single instruction (T12)
static __device__ __forceinline__ unsigned cvtpk(float lo, float hi) {
    unsigned r; asm("v_cvt_pk_bf16_f32 %0, %1, %2" : "=v"(r) : "v"(lo), "v"(hi));
    return r;
}

// exchange x.lanes[32:63] <-> y.lanes[0:31] (cross-half move)
static __device__ __forceinline__ void plswap(unsigned &x, unsigned &y) {
#if __has_builtin(__builtin_amdgcn_permlane32_swap)
    typedef __attribute__((ext_vector_type(2))) unsigned int u32x2;
    u32x2 t = __builtin_amdgcn_permlane32_swap(x, y, false, false);
    x = t.x; y = t.y;
#else
    asm volatile("v_permlane32_swap_b32 %0, %1" : "+v"(x), "+v"(y));
#endif
}

static __device__ __forceinline__ unsigned short f2bf(float f) {
    union { float f; unsigned u; } x; x.f = f;
    unsigned r = x.u + 0x7fffu + ((x.u >> 16) & 1u);
    return (unsigned short)(r >> 16);
}

// Prep (Q pass REMOVED — Q is converted in-register inside attn8):
//  [0,4096)     : k -> relu+cvt+head-relayout
//  [4096,5120)  : v -> relu+cvt+TRANSPOSE -> vt
//  [5120,6144)  : w -> cvt
__global__ __launch_bounds__(256) void prep_all(const float* __restrict__ k,
                                                const float* __restrict__ v,
                                                const float* __restrict__ w,
                                                unsigned short* __restrict__ kh,
                                                unsigned short* __restrict__ vt,
                                                unsigned short* __restrict__ wb) {
    const int bid = blockIdx.x;
    const int tid = threadIdx.x;
    if (bid < 4096) {
        long i = ((long)bid * 256 + tid) * 4;
        int dh = (int)(i & 63);
        int h  = (int)((i >> 6) & (Hc - 1));
        int s  = (int)((i >> 10) & (Sc - 1));
        int b  = (int)(i >> 21);
        float4 x = *reinterpret_cast<const float4*>(k + i);
        long o = (((long)b * Hc + h) * Sc + s) * 64 + dh;
        ushort4 r;
        r.x = f2bf(fmaxf(x.x, 0.f));
        r.y = f2bf(fmaxf(x.y, 0.f));
        r.z = f2bf(fmaxf(x.z, 0.f));
        r.w = f2bf(fmaxf(x.w, 0.f));
        *reinterpret_cast<ushort4*>(kh + o) = r;
    } else if (bid < 5120) {
        __shared__ unsigned short lds[64][66];   // [s][dh], stride 66
        const int lb = bid - 4096;
        const int st = lb & (Sc / 64 - 1);
        const int bh = lb >> 5;
        const int b = bh >> 4, h = bh & 15;
#pragma unroll
        for (int i = 0; i < 4; ++i) {
            int srow = (tid >> 4) + i * 16;
            int scol = (tid & 15) * 4;
            float4 x = *(const float4*)(v + ((long)b * Sc + st * 64 + srow) * Dc + h * 64 + scol);
            lds[srow][scol + 0] = f2bf(fmaxf(x.x, 0.f));
            lds[srow][scol + 1] = f2bf(fmaxf(x.y, 0.f));
            lds[srow][scol + 2] = f2bf(fmaxf(x.z, 0.f));
            lds[srow][scol + 3] = f2bf(fmaxf(x.w, 0.f));
        }
        __syncthreads();
#pragma unroll
        for (int i = 0; i < 2; ++i) {
            int dh = (tid >> 3) + i * 32;
            int sc = (tid & 7) * 8;
            union { unsigned short u[8]; s16x8 v8; } o;
#pragma unroll
            for (int j = 0; j < 8; ++j) o.u[j] = lds[sc + j][dh];
            *(s16x8*)(vt + ((long)bh * 64 + dh) * Sc + st * 64 + sc) = o.v8;
        }
    } else {
        const int lb = bid - 5120;
        long i = ((long)lb * 256 + tid) * 4;
        float4 x = *reinterpret_cast<const float4*>(w + i);
        ushort4 r;
        r.x = f2bf(x.x); r.y = f2bf(x.y); r.z = f2bf(x.z); r.w = f2bf(x.w);
        *reinterpret_cast<ushort4*>(wb + i) = r;
    }
}

// Flash attention (r18 structure; Q prep FUSED): 8 waves/block, each wave owns
// a DISTINCT 32-q tile (256 q/block); Q read directly from fp32 input and
// relu+scale+cvt'd in-register in the prologue (removes the entire Q prep
// pass: -16.8MB fp32 read, -8.4MB bf16 write, -8.4MB bf16 re-read).
// ONE K/V stage feeds all 8 waves; grid 256 = 1 block/CU; KVBLK=64
// double-buffered, one barrier per tile; per-block kv phase offset.
// Swizzle g(row)=(row&7)^((row>>3)&3): linear LDS dest + inverse-swizzled
// global source + swizzled ds_read (bank conflicts = 0, r16).
// Math: S^T = K*Q^T 32x32x16; static-max exp2 softmax in-lane (q,k ReLU'd =>
// scores in [0,~7.2]); cvt_pk + permlane32_swap builds PV B-frags;
// O^T = V^T*P^T.
__global__ __launch_bounds__(512, 1) void attn8(const float* __restrict__ qf,
                                                const unsigned short* __restrict__ kh,
                                                const unsigned short* __restrict__ vt,
                                                unsigned short* __restrict__ xout) {
    __shared__ unsigned short Klds[2][64 * 64];  // [kv][dh], swizzled chunks
    __shared__ unsigned short Vlds[2][64 * 64];  // [dh][kv], swizzled chunks

    const int tid = threadIdx.x;
    const int l = tid & 63, w = tid >> 6;        // w in 0..7
    const int r32 = l & 31, hl = l >> 5;
    // XCD swizzle (bijective: 256 % 8 == 0): 32 consecutive jobs per XCD
    const int job = (blockIdx.x & 7) * 32 + (blockIdx.x >> 3);
    const int qb = job & 7;               // 8 q-super-blocks (256 q) per bh
    const int bh = job >> 3;
    const int phase = job & 31;           // kv start-tile offset (commutative)
    const int bq = bh >> 4, hq = bh & 15;

    const unsigned short* Kp = kh + (long)bh * Sc * 64;
    const unsigned short* Vp = vt + (long)bh * 64 * Sc;

    // Q^T B-frags from RAW fp32 q: lane holds Q[q0 + r32][ds*16 + hl*8 + i],
    // relu + softmax-scale (1/8 * log2e) + bf16, packed via cvt_pk (RTNE).
    const float QS = 0.18033688011112042f;   // 0.125 * log2(e)
    const float* Qf = qf + ((long)bq * Sc + qb * 256 + w * 32 + r32) * Dc + hq * 64;
    s16x8 qbf[4];
#pragma unroll
    for (int ds = 0; ds < 4; ++ds) {
        float4 f0 = *(const float4*)(Qf + ds * 16 + hl * 8);
        float4 f1 = *(const float4*)(Qf + ds * 16 + hl * 8 + 4);
        union { unsigned u[4]; s16x8 v8; } qq;
        qq.u[0] = cvtpk(fmaxf(f0.x, 0.f) * QS, fmaxf(f0.y, 0.f) * QS);
        qq.u[1] = cvtpk(fmaxf(f0.z, 0.f) * QS, fmaxf(f0.w, 0.f) * QS);
        qq.u[2] = cvtpk(fmaxf(f1.x, 0.f) * QS, fmaxf(f1.y, 0.f) * QS);
        qq.u[3] = cvtpk(fmaxf(f1.z, 0.f) * QS, fmaxf(f1.w, 0.f) * QS);
        qbf[ds] = qq.v8;
    }

    f32x16 acc0 = {0,0,0,0,0,0,0,0,0,0,0,0,0,0,0,0};
    f32x16 acc1 = {0,0,0,0,0,0,0,0,0,0,0,0,0,0,0,0};
    float denom = 0.f;

    // stage one 64-kv tile: 512 K + 512 V chunks (16B) over 8 waves ->
    // ONE K + ONE V gload per thread. LDS dest wave-uniform + lane*16.
    auto stage = [&](int buf, int kv0) {
        const int cbase = w * 64;
        const int chunk = cbase + l;
        const int row = chunk >> 3, cc = chunk & 7;
        const int scc = cc ^ swz(row);
        const unsigned short* ksrc = Kp + (long)(kv0 + row) * 64 + scc * 8;
        const unsigned short* vsrc = Vp + (long)row * Sc + kv0 + scc * 8;
        __builtin_amdgcn_global_load_lds((const AS1 unsigned int*)(const void*)ksrc,
                                         (AS3 unsigned int*)(void*)&Klds[buf][cbase * 8],
                                         16, 0, 0);
        __builtin_amdgcn_global_load_lds((const AS1 unsigned int*)(const void*)vsrc,
                                         (AS3 unsigned int*)(void*)&Vlds[buf][cbase * 8],
                                         16, 0, 0);
    };

    auto compute = [&](int buf) {
        const unsigned short* KB = &Klds[buf][0];
        const unsigned short* VB = &Vlds[buf][0];
        unsigned Bw[4][4];   // [slice s][word] PV B-frags for kv slices of 16
#pragma unroll
        for (int kt = 0; kt < 2; ++kt) {
            f32x16 st = {0,0,0,0,0,0,0,0,0,0,0,0,0,0,0,0};
#pragma unroll
            for (int ds = 0; ds < 4; ++ds) {
                const int row = kt * 32 + r32;
                const int cc = ((ds * 2 + hl) ^ swz(row));
                s16x8 ka = *(const s16x8*)(KB + row * 64 + cc * 8);
                st = __builtin_amdgcn_mfma_f32_32x32x16_bf16(ka, qbf[ds], st, 0, 0, 0);
            }
            float p[16];
#pragma unroll
            for (int i = 0; i < 16; ++i) p[i] = fexp2(st[i]);
            denom += (((p[0] + p[1]) + (p[2] + p[3])) + ((p[4] + p[5]) + (p[6] + p[7])))
                   + (((p[8] + p[9]) + (p[10] + p[11])) + ((p[12] + p[13]) + (p[14] + p[15])));
            unsigned a0 = cvtpk(p[0], p[1]),   b0 = cvtpk(p[2], p[3]);
            unsigned c0 = cvtpk(p[4], p[5]),   d0 = cvtpk(p[6], p[7]);
            unsigned a1 = cvtpk(p[8], p[9]),   b1 = cvtpk(p[10], p[11]);
            unsigned c1 = cvtpk(p[12], p[13]), d1 = cvtpk(p[14], p[15]);
            plswap(a0, c0); plswap(b0, d0);
            plswap(a1, c1); plswap(b1, d1);
            Bw[kt * 2 + 0][0] = a0; Bw[kt * 2 + 0][1] = b0;
            Bw[kt * 2 + 0][2] = c0; Bw[kt * 2 + 0][3] = d0;
            Bw[kt * 2 + 1][0] = a1; Bw[kt * 2 + 1][1] = b1;
            Bw[kt * 2 + 1][2] = c1; Bw[kt * 2 + 1][3] = d1;
        }
#pragma unroll
        for (int dt = 0; dt < 2; ++dt) {
#pragma unroll
            for (int s = 0; s < 4; ++s) {
                const int row = dt * 32 + r32;
                const int cc = ((s * 2 + hl) ^ swz(row));
                s16x8 va = *(const s16x8*)(VB + row * 64 + cc * 8);
                union { unsigned u[4]; s16x8 v8; } bp;
                bp.u[0] = Bw[s][0]; bp.u[1] = Bw[s][1];
                bp.u[2] = Bw[s][2]; bp.u[3] = Bw[s][3];
                if (dt == 0)
                    acc0 = __builtin_amdgcn_mfma_f32_32x32x16_bf16(va, bp.v8, acc0, 0, 0, 0);
                else
                    acc1 = __builtin_amdgcn_mfma_f32_32x32x16_bf16(va, bp.v8, acc1, 0, 0, 0);
            }
        }
    };

    // 2-phase pipeline with phase-offset tile order (all 32 tiles, wrapped)
    stage(0, phase * 64);
    __syncthreads();
    int cur = 0;
    for (int t = 0; t < Sc / 64 - 1; ++t) {
        stage(cur ^ 1, ((t + 1 + phase) & (Sc / 64 - 1)) * 64);
        compute(cur);
        __syncthreads();
        cur ^= 1;
    }
    compute(cur);

    float dn = denom + __shfl_xor(denom, 32);
    const float inv = 1.0f / dn;
    unsigned short* Xrow = xout + ((long)bq * Sc + qb * 256 + w * 32 + r32) * Dc + hq * 64;
#pragma unroll
    for (int dt = 0; dt < 2; ++dt) {
        const f32x16& A = dt ? acc1 : acc0;
#pragma unroll
        for (int rg = 0; rg < 4; ++rg) {
            unsigned wlo = cvtpk(A[rg * 4 + 0] * inv, A[rg * 4 + 1] * inv);
            unsigned whi = cvtpk(A[rg * 4 + 2] * inv, A[rg * 4 + 3] * inv);
            uint2 wv; wv.x = wlo; wv.y = whi;
            *reinterpret_cast<uint2*>(Xrow + dt * 32 + rg * 8 + hl * 4) = wv;
        }
    }
}

// Output projection: out = relu(X @ W^T + b), X:[4096x1024] bf16, W row-major.
// Tiled LDS GEMM: BM=128, BN=128, BK=64, 4 waves (each 32m x 128n strip),
// double-buffered global_load_lds staging with the swz(row) involution
// swizzle, one barrier per K-stage. Grid 256 = 1 block/CU, XCD-swizzled.
__global__ __launch_bounds__(256, 2) void proj256(const unsigned short* __restrict__ X,
                                                  const unsigned short* __restrict__ Wb,
                                                  const float* __restrict__ bias,
                                                  float* __restrict__ out) {
    __shared__ unsigned short Xlds[2][128 * 64];  // [m][k], swizzled chunks
    __shared__ unsigned short Wlds[2][128 * 64];  // [n][k], swizzled chunks

    const int tid = threadIdx.x;
    const int l = tid & 63, w = tid >> 6;
    const int r32 = l & 31, hl = l >> 5;
    // XCD swizzle (bijective: 256 % 8 == 0)
    const int job = (blockIdx.x & 7) * 32 + (blockIdx.x >> 3);
    const int nb = job & 7;     // 8 n-tiles of 128
    const int mb = job >> 3;    // 32 m-tiles of 128

    const unsigned short* Xp = X + (long)mb * 128 * Dc;
    const unsigned short* Wp = Wb + (long)nb * 128 * Dc;

    f32x16 acc[4];
#pragma unroll
    for (int nt = 0; nt < 4; ++nt)
        acc[nt] = (f32x16){0,0,0,0,0,0,0,0,0,0,0,0,0,0,0,0};

    auto stage = [&](int buf, int k0) {
#pragma unroll
        for (int j = 0; j < 4; ++j) {
            const int chunk = j * 256 + tid;
            const int row = chunk >> 3, cc = chunk & 7;
            const int scc = cc ^ swz(row);
            const unsigned short* xsrc = Xp + (long)row * Dc + k0 + scc * 8;
            const unsigned short* wsrc = Wp + (long)row * Dc + k0 + scc * 8;
            __builtin_amdgcn_global_load_lds((const AS1 unsigned int*)(const void*)xsrc,
                                             (AS3 unsigned int*)(void*)&Xlds[buf][chunk * 8],
                                             16, 0, 0);
            __builtin_amdgcn_global_load_lds((const AS1 unsigned int*)(const void*)wsrc,
                                             (AS3 unsigned int*)(void*)&Wlds[buf][chunk * 8],
                                             16, 0, 0);
        }
    };

    auto compute = [&](int buf) {
        const unsigned short* XB = &Xlds[buf][0];
        const unsigned short* WB = &Wlds[buf][0];
#pragma unroll
        for (int ks = 0; ks < 4; ++ks) {   // 4 k-subs of 16 within BK=64
            const int arow = w * 32 + r32;
            const int acc_ = ((ks * 2 + hl) ^ swz(arow));
            s16x8 af = *(const s16x8*)(XB + arow * 64 + acc_ * 8);
#pragma unroll
            for (int nt = 0; nt < 4; ++nt) {
                const int brow = nt * 32 + r32;
                const int bcc = ((ks * 2 + hl) ^ swz(brow));
                s16x8 bf = *(const s16x8*)(WB + brow * 64 + bcc * 8);
                acc[nt] = __builtin_amdgcn_mfma_f32_32x32x16_bf16(af, bf, acc[nt], 0, 0, 0);
            }
        }
    };

    stage(0, 0);
    __syncthreads();
    int cur = 0;
    for (int t = 0; t < Dc / 64 - 1; ++t) {
        stage(cur ^ 1, (t + 1) * 64);
        compute(cur);
        __syncthreads();
        cur ^= 1;
    }
    compute(cur);

    // epilogue: C row m = (reg&3)+8*(reg>>2)+4*hl (+ wave strip), col n = r32
#pragma unroll
    for (int nt = 0; nt < 4; ++nt) {
        const float bv = bias[nb * 128 + nt * 32 + r32];
#pragma unroll
        for (int j = 0; j < 16; ++j) {
            const int m = (j & 3) + 8 * (j >> 2) + 4 * hl;
            out[((long)(mb * 128 + w * 32 + m)) * Dc + nb * 128 + nt * 32 + r32] =
                fmaxf(acc[nt][j] + bv, 0.f);
        }
    }
}

extern "C" void kernel_launch(void* const* d_in, const int* in_sizes, int n_in,
                              void* d_out, int out_size, void* d_ws, size_t ws_size,
                              hipStream_t stream) {
    const float* q    = (const float*)d_in[0];
    const float* k    = (const float*)d_in[1];
    const float* v    = (const float*)d_in[2];
    const float* w    = (const float*)d_in[3];
    const float* bias = (const float*)d_in[4];
    float* out = (float*)d_out;

    unsigned short* ws = (unsigned short*)d_ws;
    unsigned short* kh = ws;                   // 4194304 bf16
    unsigned short* vt = kh + 4194304;         // V^T: [B*H][64][2048]
    unsigned short* wb = vt + 4194304;         // 1048576 bf16
    unsigned short* X  = wb + 1048576;         // 4194304 bf16

    prep_all<<<6144, 256, 0, stream>>>(k, v, w, kh, vt, wb);
    attn8<<<Bc * Hc * (Sc / 256), 512, 0, stream>>>(q, kh, vt, X);
    proj256<<<(Bc * Sc / 128) * (Dc / 128), 256, 0, stream>>>(X, wb, bias, out);
}

// Round 20
// 79.280 us; speedup vs baseline: 1.0278x; 1.0278x over previous
//
#include <hip/hip_runtime.h>
#include <hip/hip_bf16.h>

#define Bc 2
#define Hc 16
#define Sc 2048
#define Dc 1024

typedef __attribute__((ext_vector_type(8))) short s16x8;
typedef __attribute__((ext_vector_type(4))) float f32x4;
typedef __attribute__((ext_vector_type(16))) float f32x16;

#define AS1 __attribute__((address_space(1)))
#define AS3 __attribute__((address_space(3)))

// LDS chunk swizzle (involution): distinct across rows differing by 8/16/24
// (the ds_read alias groups) -> bank-conflict-free (verified r16: 4.2M -> 0).
static __device__ __forceinline__ int swz(int row) {
    return (row & 7) ^ ((row >> 3) & 3);
}

static __device__ __forceinline__ float fexp2(float x) {
#if __has_builtin(__builtin_amdgcn_exp2f)
    return __builtin_amdgcn_exp2f(x);
#else
    float r; asm("v_exp_f32 %0, %1" : "=v"(r) : "v"(x)); return r;
#endif
}

// pack two f32 -> one u32 of 2 bf16 (RTNE), single instruction (T12)
static __device__ __forceinline__ unsigned cvtpk(float lo, float hi) {
    unsigned r; asm("v_cvt_pk_bf16_f32 %0, %1, %2" : "=v"(r) : "v"(lo), "v"(hi));
    return r;
}

// exchange x.lanes[32:63] <-> y.lanes[0:31] (cross-half move)
static __device__ __forceinline__ void plswap(unsigned &x, unsigned &y) {
#if __has_builtin(__builtin_amdgcn_permlane32_swap)
    typedef __attribute__((ext_vector_type(2))) unsigned int u32x2;
    u32x2 t = __builtin_amdgcn_permlane32_swap(x, y, false, false);
    x = t.x; y = t.y;
#else
    asm volatile("v_permlane32_swap_b32 %0, %1" : "+v"(x), "+v"(y));
#endif
}

static __device__ __forceinline__ unsigned short f2bf(float f) {
    union { float f; unsigned u; } x; x.f = f;
    unsigned r = x.u + 0x7fffu + ((x.u >> 16) & 1u);
    return (unsigned short)(r >> 16);
}

// ALL prep fused into one dispatch (branch on blockIdx; uniform per block)
__global__ __launch_bounds__(256) void prep_all(const float* __restrict__ q,
                                                const float* __restrict__ k,
                                                const float* __restrict__ v,
                                                const float* __restrict__ w,
                                                unsigned short* __restrict__ qh,
                                                unsigned short* __restrict__ kh,
                                                unsigned short* __restrict__ vt,
                                                unsigned short* __restrict__ wb) {
    const int bid = blockIdx.x;
    const int tid = threadIdx.x;
    if (bid < 8192) {
        const bool isQ = bid < 4096;
        const float* src = isQ ? q : k;
        unsigned short* dst = isQ ? qh : kh;
        // fold softmax scale (1/8) and log2(e) into Q: scores in exp2 domain
        const float scale = isQ ? 0.18033688011112042f : 1.0f;
        long i = ((long)(bid & 4095) * 256 + tid) * 4;
        int dh = (int)(i & 63);
        int h  = (int)((i >> 6) & (Hc - 1));
        int s  = (int)((i >> 10) & (Sc - 1));
        int b  = (int)(i >> 21);
        float4 x = *reinterpret_cast<const float4*>(src + i);
        long o = (((long)b * Hc + h) * Sc + s) * 64 + dh;
        ushort4 r;
        r.x = f2bf(fmaxf(x.x, 0.f) * scale);
        r.y = f2bf(fmaxf(x.y, 0.f) * scale);
        r.z = f2bf(fmaxf(x.z, 0.f) * scale);
        r.w = f2bf(fmaxf(x.w, 0.f) * scale);
        *reinterpret_cast<ushort4*>(dst + o) = r;
    } else if (bid < 9216) {
        __shared__ unsigned short lds[64][66];   // [s][dh], stride 66
        const int lb = bid - 8192;
        const int st = lb & (Sc / 64 - 1);
        const int bh = lb >> 5;
        const int b = bh >> 4, h = bh & 15;
#pragma unroll
        for (int i = 0; i < 4; ++i) {
            int srow = (tid >> 4) + i * 16;
            int scol = (tid & 15) * 4;
            float4 x = *(const float4*)(v + ((long)b * Sc + st * 64 + srow) * Dc + h * 64 + scol);
            lds[srow][scol + 0] = f2bf(fmaxf(x.x, 0.f));
            lds[srow][scol + 1] = f2bf(fmaxf(x.y, 0.f));
            lds[srow][scol + 2] = f2bf(fmaxf(x.z, 0.f));
            lds[srow][scol + 3] = f2bf(fmaxf(x.w, 0.f));
        }
        __syncthreads();
#pragma unroll
        for (int i = 0; i < 2; ++i) {
            int dh = (tid >> 3) + i * 32;
            int sc = (tid & 7) * 8;
            union { unsigned short u[8]; s16x8 v8; } o;
#pragma unroll
            for (int j = 0; j < 8; ++j) o.u[j] = lds[sc + j][dh];
            *(s16x8*)(vt + ((long)bh * 64 + dh) * Sc + st * 64 + sc) = o.v8;
        }
    } else {
        const int lb = bid - 9216;
        long i = ((long)lb * 256 + tid) * 4;
        float4 x = *reinterpret_cast<const float4*>(w + i);
        ushort4 r;
        r.x = f2bf(x.x); r.y = f2bf(x.y); r.z = f2bf(x.z); r.w = f2bf(x.w);
        *reinterpret_cast<ushort4*>(wb + i) = r;
    }
}

// Flash attention (r18 best-known): 8 waves/block, each wave owns a DISTINCT
// 32-q tile (256 q/block); ONE K/V stage feeds all 8 waves (block-amortized
// staging, -50% vs 4-wave). Grid 256 = 1 block/CU. KVBLK=64 double-buffered,
// one barrier per tile; per-block kv phase offset (commutative).
// Swizzle g(row)=(row&7)^((row>>3)&3): linear LDS dest + inverse-swizzled
// global source + swizzled ds_read (bank conflicts = 0).
// Math: S^T = K*Q^T 32x32x16; static-max exp2 softmax in-lane (q,k ReLU'd =>
// scores in [0,~7.2]); cvt_pk + permlane32_swap builds PV B-frags;
// O^T = V^T*P^T.
__global__ __launch_bounds__(512, 1) void attn8(const unsigned short* __restrict__ qh,
                                                const unsigned short* __restrict__ kh,
                                                const unsigned short* __restrict__ vt,
                                                unsigned short* __restrict__ xout) {
    __shared__ unsigned short Klds[2][64 * 64];  // [kv][dh], swizzled chunks
    __shared__ unsigned short Vlds[2][64 * 64];  // [dh][kv], swizzled chunks

    const int tid = threadIdx.x;
    const int l = tid & 63, w = tid >> 6;        // w in 0..7
    const int r32 = l & 31, hl = l >> 5;
    // XCD swizzle (bijective: 256 % 8 == 0): 32 consecutive jobs per XCD
    const int job = (blockIdx.x & 7) * 32 + (blockIdx.x >> 3);
    const int qb = job & 7;               // 8 q-super-blocks (256 q) per bh
    const int bh = job >> 3;
    const int phase = job & 31;           // kv start-tile offset (commutative)

    const unsigned short* Qp = qh + ((long)bh * Sc + qb * 256 + w * 32) * 64;
    const unsigned short* Kp = kh + (long)bh * Sc * 64;
    const unsigned short* Vp = vt + (long)bh * 64 * Sc;

    // Q^T B-frags: lane holds Q[q0 + r32][ds*16 + hl*8 + i]
    s16x8 qbf[4];
#pragma unroll
    for (int ds = 0; ds < 4; ++ds)
        qbf[ds] = *(const s16x8*)(Qp + r32 * 64 + ds * 16 + hl * 8);

    f32x16 acc0 = {0,0,0,0,0,0,0,0,0,0,0,0,0,0,0,0};
    f32x16 acc1 = {0,0,0,0,0,0,0,0,0,0,0,0,0,0,0,0};
    float denom = 0.f;

    // stage one 64-kv tile: 512 K + 512 V chunks (16B) over 8 waves ->
    // ONE K + ONE V gload per thread. LDS dest wave-uniform + lane*16.
    auto stage = [&](int buf, int kv0) {
        const int cbase = w * 64;
        const int chunk = cbase + l;
        const int row = chunk >> 3, cc = chunk & 7;
        const int scc = cc ^ swz(row);
        const unsigned short* ksrc = Kp + (long)(kv0 + row) * 64 + scc * 8;
        const unsigned short* vsrc = Vp + (long)row * Sc + kv0 + scc * 8;
        __builtin_amdgcn_global_load_lds((const AS1 unsigned int*)(const void*)ksrc,
                                         (AS3 unsigned int*)(void*)&Klds[buf][cbase * 8],
                                         16, 0, 0);
        __builtin_amdgcn_global_load_lds((const AS1 unsigned int*)(const void*)vsrc,
                                         (AS3 unsigned int*)(void*)&Vlds[buf][cbase * 8],
                                         16, 0, 0);
    };

    auto compute = [&](int buf) {
        const unsigned short* KB = &Klds[buf][0];
        const unsigned short* VB = &Vlds[buf][0];
        unsigned Bw[4][4];   // [slice s][word] PV B-frags for kv slices of 16
#pragma unroll
        for (int kt = 0; kt < 2; ++kt) {
            f32x16 st = {0,0,0,0,0,0,0,0,0,0,0,0,0,0,0,0};
#pragma unroll
            for (int ds = 0; ds < 4; ++ds) {
                const int row = kt * 32 + r32;
                const int cc = ((ds * 2 + hl) ^ swz(row));
                s16x8 ka = *(const s16x8*)(KB + row * 64 + cc * 8);
                st = __builtin_amdgcn_mfma_f32_32x32x16_bf16(ka, qbf[ds], st, 0, 0, 0);
            }
            float p[16];
#pragma unroll
            for (int i = 0; i < 16; ++i) p[i] = fexp2(st[i]);
            denom += (((p[0] + p[1]) + (p[2] + p[3])) + ((p[4] + p[5]) + (p[6] + p[7])))
                   + (((p[8] + p[9]) + (p[10] + p[11])) + ((p[12] + p[13]) + (p[14] + p[15])));
            unsigned a0 = cvtpk(p[0], p[1]),   b0 = cvtpk(p[2], p[3]);
            unsigned c0 = cvtpk(p[4], p[5]),   d0 = cvtpk(p[6], p[7]);
            unsigned a1 = cvtpk(p[8], p[9]),   b1 = cvtpk(p[10], p[11]);
            unsigned c1 = cvtpk(p[12], p[13]), d1 = cvtpk(p[14], p[15]);
            plswap(a0, c0); plswap(b0, d0);
            plswap(a1, c1); plswap(b1, d1);
            Bw[kt * 2 + 0][0] = a0; Bw[kt * 2 + 0][1] = b0;
            Bw[kt * 2 + 0][2] = c0; Bw[kt * 2 + 0][3] = d0;
            Bw[kt * 2 + 1][0] = a1; Bw[kt * 2 + 1][1] = b1;
            Bw[kt * 2 + 1][2] = c1; Bw[kt * 2 + 1][3] = d1;
        }
#pragma unroll
        for (int dt = 0; dt < 2; ++dt) {
#pragma unroll
            for (int s = 0; s < 4; ++s) {
                const int row = dt * 32 + r32;
                const int cc = ((s * 2 + hl) ^ swz(row));
                s16x8 va = *(const s16x8*)(VB + row * 64 + cc * 8);
                union { unsigned u[4]; s16x8 v8; } bp;
                bp.u[0] = Bw[s][0]; bp.u[1] = Bw[s][1];
                bp.u[2] = Bw[s][2]; bp.u[3] = Bw[s][3];
                if (dt == 0)
                    acc0 = __builtin_amdgcn_mfma_f32_32x32x16_bf16(va, bp.v8, acc0, 0, 0, 0);
                else
                    acc1 = __builtin_amdgcn_mfma_f32_32x32x16_bf16(va, bp.v8, acc1, 0, 0, 0);
            }
        }
    };

    // 2-phase pipeline with phase-offset tile order (all 32 tiles, wrapped)
    stage(0, phase * 64);
    __syncthreads();
    int cur = 0;
    for (int t = 0; t < Sc / 64 - 1; ++t) {
        stage(cur ^ 1, ((t + 1 + phase) & (Sc / 64 - 1)) * 64);
        compute(cur);
        __syncthreads();
        cur ^= 1;
    }
    compute(cur);

    float dn = denom + __shfl_xor(denom, 32);
    const float inv = 1.0f / dn;
    const int b = bh >> 4, h = bh & 15;
    unsigned short* Xrow = xout + ((long)b * Sc + qb * 256 + w * 32 + r32) * Dc + h * 64;
#pragma unroll
    for (int dt = 0; dt < 2; ++dt) {
        const f32x16& A = dt ? acc1 : acc0;
#pragma unroll
        for (int rg = 0; rg < 4; ++rg) {
            unsigned wlo = cvtpk(A[rg * 4 + 0] * inv, A[rg * 4 + 1] * inv);
            unsigned whi = cvtpk(A[rg * 4 + 2] * inv, A[rg * 4 + 3] * inv);
            uint2 wv; wv.x = wlo; wv.y = whi;
            *reinterpret_cast<uint2*>(Xrow + dt * 32 + rg * 8 + hl * 4) = wv;
        }
    }
}

// Output projection: out = relu(X @ W^T + b), X:[4096x1024] bf16, W row-major.
// Tiled LDS GEMM: BM=128, BN=128, BK=64, 4 waves (each 32m x 128n strip),
// double-buffered global_load_lds staging with the swz(row) involution
// swizzle, one barrier per K-stage. Grid 256 = 1 block/CU, XCD-swizzled.
__global__ __launch_bounds__(256, 2) void proj256(const unsigned short* __restrict__ X,
                                                  const unsigned short* __restrict__ Wb,
                                                  const float* __restrict__ bias,
                                                  float* __restrict__ out) {
    __shared__ unsigned short Xlds[2][128 * 64];  // [m][k], swizzled chunks
    __shared__ unsigned short Wlds[2][128 * 64];  // [n][k], swizzled chunks

    const int tid = threadIdx.x;
    const int l = tid & 63, w = tid >> 6;
    const int r32 = l & 31, hl = l >> 5;
    // XCD swizzle (bijective: 256 % 8 == 0)
    const int job = (blockIdx.x & 7) * 32 + (blockIdx.x >> 3);
    const int nb = job & 7;     // 8 n-tiles of 128
    const int mb = job >> 3;    // 32 m-tiles of 128

    const unsigned short* Xp = X + (long)mb * 128 * Dc;
    const unsigned short* Wp = Wb + (long)nb * 128 * Dc;

    f32x16 acc[4];
#pragma unroll
    for (int nt = 0; nt < 4; ++nt)
        acc[nt] = (f32x16){0,0,0,0,0,0,0,0,0,0,0,0,0,0,0,0};

    auto stage = [&](int buf, int k0) {
#pragma unroll
        for (int j = 0; j < 4; ++j) {
            const int chunk = j * 256 + tid;
            const int row = chunk >> 3, cc = chunk & 7;
            const int scc = cc ^ swz(row);
            const unsigned short* xsrc = Xp + (long)row * Dc + k0 + scc * 8;
            const unsigned short* wsrc = Wp + (long)row * Dc + k0 + scc * 8;
            __builtin_amdgcn_global_load_lds((const AS1 unsigned int*)(const void*)xsrc,
                                             (AS3 unsigned int*)(void*)&Xlds[buf][chunk * 8],
                                             16, 0, 0);
            __builtin_amdgcn_global_load_lds((const AS1 unsigned int*)(const void*)wsrc,
                                             (AS3 unsigned int*)(void*)&Wlds[buf][chunk * 8],
                                             16, 0, 0);
        }
    };

    auto compute = [&](int buf) {
        const unsigned short* XB = &Xlds[buf][0];
        const unsigned short* WB = &Wlds[buf][0];
#pragma unroll
        for (int ks = 0; ks < 4; ++ks) {   // 4 k-subs of 16 within BK=64
            const int arow = w * 32 + r32;
            const int acc_ = ((ks * 2 + hl) ^ swz(arow));
            s16x8 af = *(const s16x8*)(XB + arow * 64 + acc_ * 8);
#pragma unroll
            for (int nt = 0; nt < 4; ++nt) {
                const int brow = nt * 32 + r32;
                const int bcc = ((ks * 2 + hl) ^ swz(brow));
                s16x8 bf = *(const s16x8*)(WB + brow * 64 + bcc * 8);
                acc[nt] = __builtin_amdgcn_mfma_f32_32x32x16_bf16(af, bf, acc[nt], 0, 0, 0);
            }
        }
    };

    stage(0, 0);
    __syncthreads();
    int cur = 0;
    for (int t = 0; t < Dc / 64 - 1; ++t) {
        stage(cur ^ 1, (t + 1) * 64);
        compute(cur);
        __syncthreads();
        cur ^= 1;
    }
    compute(cur);

    // epilogue: C row m = (reg&3)+8*(reg>>2)+4*hl (+ wave strip), col n = r32
#pragma unroll
    for (int nt = 0; nt < 4; ++nt) {
        const float bv = bias[nb * 128 + nt * 32 + r32];
#pragma unroll
        for (int j = 0; j < 16; ++j) {
            const int m = (j & 3) + 8 * (j >> 2) + 4 * hl;
            out[((long)(mb * 128 + w * 32 + m)) * Dc + nb * 128 + nt * 32 + r32] =
                fmaxf(acc[nt][j] + bv, 0.f);
        }
    }
}

extern "C" void kernel_launch(void* const* d_in, const int* in_sizes, int n_in,
                              void* d_out, int out_size, void* d_ws, size_t ws_size,
                              hipStream_t stream) {
    const float* q    = (const float*)d_in[0];
    const float* k    = (const float*)d_in[1];
    const float* v    = (const float*)d_in[2];
    const float* w    = (const float*)d_in[3];
    const float* bias = (const float*)d_in[4];
    float* out = (float*)d_out;

    unsigned short* ws = (unsigned short*)d_ws;
    unsigned short* qh = ws;                   // 4194304 bf16
    unsigned short* kh = qh + 4194304;
    unsigned short* vt = kh + 4194304;         // V^T: [B*H][64][2048]
    unsigned short* wb = vt + 4194304;         // 1048576 bf16
    unsigned short* X  = wb + 1048576;         // 4194304 bf16

    prep_all<<<10240, 256, 0, stream>>>(q, k, v, w, qh, kh, vt, wb);
    attn8<<<Bc * Hc * (Sc / 256), 512, 0, stream>>>(qh, kh, vt, X);
    proj256<<<(Bc * Sc / 128) * (Dc / 128), 256, 0, stream>>>(X, wb, bias, out);
}